// Round 1
// baseline (149.376 us; speedup 1.0000x reference)
//
#include <hip/hip_runtime.h>

// ChamferLoss: B=4, N=M=8192, D=3, fp32. Scalar out.
// MFMA split-f16 (validated EXACT r6-r15): A = refs (LDS), B = queries (regs),
// in-lane min3 tree, VGPR-dest asm MFMA (r13), 2+2 grouped hazard tail (r15),
// __launch_bounds__(256,8) occupancy band (r16).
// r17: (a) hoist the 16x-redundant split16/frag packing into a one-shot
// presplit kernel (main-kernel staging = pure 16B vector copy, B-frags = one
// 16B load); (b) fuse the cross-slice reduction into the main kernel via
// group-last-block-done (agent-scope acq_rel counter per (dir,b,qblock)
// group) -> second kernel + its launch gap eliminated, 127/128 group
// reductions hidden under remaining compute. Presplit zeroes counters + out.

#define BATCH   4
#define NPTS    8192
#define TPB     256
#define CSLICE  512                  // ref points per block (LDS slice)
#define QT      4                    // query tiles (32 cols) per wave
#define QBLK    (4 * QT * 32)        // 512 queries per block
#define MT      (CSLICE / 32)        // 16 ref tiles per slice
#define SLICES  (NPTS / CSLICE)      // 16
#define QBLKS   (NPTS / QBLK)        // 16
#define FR_PER_SB 16384              // h8 frags per (side,b): 8192 pts * 2

typedef _Float16 h8   __attribute__((ext_vector_type(8)));
typedef float    f16v __attribute__((ext_vector_type(16)));

__device__ __forceinline__ void split16(float v, _Float16& hi, _Float16& lo) {
    hi = (_Float16)v;
    lo = (_Float16)(v - (float)hi);
}

__device__ __forceinline__ float tree16(const f16v& d) {
    float g0 = fminf(fminf(d[0],  d[1]),  d[2]);
    float g1 = fminf(fminf(d[3],  d[4]),  d[5]);
    float g2 = fminf(fminf(d[6],  d[7]),  d[8]);
    float g3 = fminf(fminf(d[9],  d[10]), d[11]);
    float g4 = fminf(fminf(d[12], d[13]), d[14]);
    float h0 = fminf(fminf(g0, g1), d[15]);
    float h1 = fminf(fminf(g2, g3), g4);
    return fminf(h0, h1);
}

// ---- one-shot fragment precompute: each point split EXACTLY as before ----
// side s: 0 = x-points, 1 = y-points. Per point: a-frag pair (ref role,
// de-interleaved [group][half][row] order so a slice is one contiguous
// 16KB run = the LDS image) and b-frag pair (query role, indexed [qi][hv]).
__global__ __launch_bounds__(TPB) void chamfer_presplit(const float* __restrict__ xg,
                                                        const float* __restrict__ yg,
                                                        h8* __restrict__ aArr,
                                                        h8* __restrict__ bArr,
                                                        unsigned* __restrict__ cnt,
                                                        float* __restrict__ out) {
    const int tid = threadIdx.x;
    const int g   = blockIdx.x * TPB + tid;        // [0, BATCH*NPTS)
    if (blockIdx.x == 0) {                         // runs before main (stream order)
        if (tid < 2 * BATCH * QBLKS) cnt[tid] = 0u;
        if (tid == 0) out[0] = 0.0f;
    }
    const int b = g >> 13, i = g & (NPTS - 1);
#pragma unroll
    for (int s = 0; s < 2; ++s) {
        const float* p = (s ? yg : xg) + ((size_t)b * NPTS + i) * 3;
        float c0 = p[0], c1 = p[1], c2 = p[2];
        _Float16 h0, l0, h1, l1, h2, l2, nh, nl, H0, L0, H1, L1, H2, L2;
        split16(c0, h0, l0);                       // a-side: RAW coords
        split16(c1, h1, l1);
        split16(c2, h2, l2);
        split16(fmaf(c0, c0, fmaf(c1, c1, c2 * c2)), nh, nl);  // |p|^2 (rn == qn)
        split16(-2.0f * c0, H0, L0);               // b-side: -2q, split AFTER scaling
        split16(-2.0f * c1, H1, L1);
        split16(-2.0f * c2, H2, L2);
        const size_t base = (size_t)(s * BATCH + b) * FR_PER_SB;
        aArr[base + (i >> 5) * 64 + (i & 31)]      =
            (h8){h0, h1, h2, l0, l1, l2, h0, h1};                           // k0..7
        aArr[base + (i >> 5) * 64 + 32 + (i & 31)] =
            (h8){h2, nh, nl, (_Float16)1.0f, (_Float16)1.0f,
                 (_Float16)0.0f, (_Float16)0.0f, (_Float16)0.0f};           // k8..15
        bArr[base + i * 2]     =
            (h8){H0, H1, H2, H0, H1, H2, L0, L1};                           // k0..7
        bArr[base + i * 2 + 1] =
            (h8){L2, (_Float16)1.0f, (_Float16)1.0f, nh, nl,
                 (_Float16)0.0f, (_Float16)0.0f, (_Float16)0.0f};           // k8..15
    }
}

__global__ __launch_bounds__(TPB, 8) void chamfer_mfma(const h8* __restrict__ aArr,
                                                       const h8* __restrict__ bArr,
                                                       float* __restrict__ partial,
                                                       unsigned* __restrict__ cnt,
                                                       float* __restrict__ out) {
    __shared__ h8 afrag[CSLICE * 2];          // 16 KB, de-interleaved (conflict-free)
    __shared__ float sred[TPB / 64];
    __shared__ int sflag;

    const int tid    = threadIdx.x;
    const int qblock = blockIdx.x;            // [0,16)
    const int slice  = blockIdx.y & (SLICES - 1);
    const int b      = blockIdx.y >> 4;       // SLICES == 16
    const int dir    = blockIdx.z;
    const int lane   = tid & 63, wave = tid >> 6;
    const int col    = lane & 31, hv = lane >> 5;

    const int sa = dir ? 0 : 1;               // ref side:   dir0 -> y, dir1 -> x
    const int sb = dir ? 1 : 0;               // query side

    // ---- stage ref A-frags: pure 16B vector copy of the precomputed image ----
    const h8* asrc = aArr + (size_t)(sa * BATCH + b) * FR_PER_SB + slice * (CSLICE * 2);
#pragma unroll
    for (int i2 = 0; i2 < (CSLICE * 2) / TPB; ++i2)            // 4x 16B per thread
        afrag[tid + i2 * TPB] = asrc[tid + i2 * TPB];

    // ---- query B-frags: one 16B load per tile (hv-selected half) ----
    const h8* bsrc = bArr + (size_t)(sb * BATCH + b) * FR_PER_SB;
    h8 bq[QT];
#pragma unroll
    for (int t = 0; t < QT; ++t) {
        const int qi = qblock * QBLK + (wave * QT + t) * 32 + col;
        bq[t] = bsrc[qi * 2 + hv];
    }
    __syncthreads();

    float cm[QT];
#pragma unroll
    for (int t = 0; t < QT; ++t) cm[t] = 3.0e38f;

    // ---- main loop: 1 A-frag read -> 2x (2 MFMAs + 2 trees); d-pair live only ----
    for (int mt = 0; mt < MT; ++mt) {
        const h8 ar = afrag[mt * 64 + lane];   // contiguous 16B/lane, conflict-free
        f16v d0, d1;
        asm("v_mfma_f32_32x32x16_f16 %0, %2, %3, 0\n\t"
            "v_mfma_f32_32x32x16_f16 %1, %2, %4, 0\n\t"
            "s_nop 7\n\t"
            "s_nop 7"
            : "=v"(d0), "=v"(d1)
            : "v"(ar), "v"(bq[0]), "v"(bq[1]));
        cm[0] = fminf(cm[0], tree16(d0));
        cm[1] = fminf(cm[1], tree16(d1));

        f16v d2, d3;
        asm("v_mfma_f32_32x32x16_f16 %0, %2, %3, 0\n\t"
            "v_mfma_f32_32x32x16_f16 %1, %2, %4, 0\n\t"
            "s_nop 7\n\t"
            "s_nop 7"
            : "=v"(d2), "=v"(d3)
            : "v"(ar), "v"(bq[2]), "v"(bq[3]));
        cm[2] = fminf(cm[2], tree16(d2));
        cm[3] = fminf(cm[3], tree16(d3));
    }

    // ---- per-slice partial: one xor32 per accumulator, coalesced stores ----
    float* pw = partial + ((size_t)(dir * BATCH + b) * SLICES + slice) * NPTS
                        + qblock * QBLK;
#pragma unroll
    for (int t = 0; t < QT; ++t) {
        cm[t] = fminf(cm[t], __shfl_xor(cm[t], 32, 64));   // hv-partner rows
        if (hv == 0)
            pw[(wave * QT + t) * 32 + col] = cm[t];        // 32 lanes, 128B coalesced
    }

    // ---- fused cross-slice reduction: last block of the (dir,b,qblock) group ----
    __syncthreads();                          // drains this block's partial stores
    const int group = (dir * BATCH + b) * QBLKS + qblock;   // [0,128)
    if (tid == 0) {
        __threadfence();                      // agent-scope release of our stores
        unsigned old = __hip_atomic_fetch_add(&cnt[group], 1u, __ATOMIC_ACQ_REL,
                                              __HIP_MEMORY_SCOPE_AGENT);
        sflag = (old == (unsigned)(SLICES - 1)) ? 1 : 0;    // acquire: L1/L2 inv
    }
    __syncthreads();
    if (!sflag) return;                       // block-uniform, no barrier divergence

    const float* pr = partial + (size_t)(dir * BATCH + b) * SLICES * NPTS
                              + qblock * QBLK;
    float sum = 0.0f;
#pragma unroll
    for (int k = 0; k < QBLK / TPB; ++k) {    // 2 queries per thread
        const int qq = tid + k * TPB;
        float v = 3.0e38f;
#pragma unroll
        for (int sl = 0; sl < SLICES; ++sl)
            v = fminf(v, pr[(size_t)sl * NPTS + qq]);      // L2-hot, coalesced
        sum += v;
    }
#pragma unroll
    for (int off = 32; off > 0; off >>= 1)
        sum += __shfl_down(sum, off, 64);
    if ((tid & 63) == 0) sred[tid >> 6] = sum;
    __syncthreads();
    if (tid == 0)
        atomicAdd(out, (sred[0] + sred[1] + sred[2] + sred[3])
                           * (1.0f / (float)(BATCH * NPTS)));
}

extern "C" void kernel_launch(void* const* d_in, const int* in_sizes, int n_in,
                              void* d_out, int out_size, void* d_ws, size_t ws_size,
                              hipStream_t stream) {
    const float* x = (const float*)d_in[0];
    const float* y = (const float*)d_in[1];
    float* out = (float*)d_out;
    char* ws = (char*)d_ws;
    float*    partial = (float*)ws;                    // 4 MB
    h8*       aArr    = (h8*)(ws + (4u << 20));        // 2 MB (2 sides x 4 b x 16K h8)
    h8*       bArr    = (h8*)(ws + (6u << 20));        // 2 MB
    unsigned* cnt     = (unsigned*)(ws + (8u << 20));  // 512 B group counters

    chamfer_presplit<<<dim3(BATCH * NPTS / TPB), TPB, 0, stream>>>(x, y, aArr, bArr,
                                                                  cnt, out);
    chamfer_mfma<<<dim3(QBLKS, BATCH * SLICES, 2), TPB, 0, stream>>>(aArr, bArr,
                                                                    partial, cnt, out);
}

// Round 2
// 80.062 us; speedup vs baseline: 1.8657x; 1.8657x over previous
//
#include <hip/hip_runtime.h>

// ChamferLoss: B=4, N=M=8192, D=3, fp32. Scalar out.
// MFMA split-f16 (validated EXACT r6-r17): A = refs (LDS), B = queries (regs),
// in-lane min3 tree, VGPR-dest asm MFMA (r13), 2+2 grouped hazard tail (r15),
// __launch_bounds__(256,8) occupancy band (r16).
// r17 LESSON: fusing the cross-slice reduction via per-block agent-scope
// release/acquire (threadfence + ACQ_REL atomic) = buffer_wbl2 + buffer_inv
// in EVERY one of 2048 blocks -> TCC serialization + L2 trashing of the
// frag arrays; chamfer_mfma 95us (3x). NEVER per-block device-scope fences.
// r18: keep the presplit kernel (one-shot split16/frag packing; main-kernel
// staging = pure 16B vector copy, B-frags = one 16B load -> ~140 VALU
// instr/thread of 16x-redundant prologue removed), revert to the separate
// stream-ordered chamfer_reduce dispatch (no fences, no atomic counters).

#define BATCH   4
#define NPTS    8192
#define TPB     256
#define CSLICE  512                  // ref points per block (LDS slice)
#define QT      4                    // query tiles (32 cols) per wave
#define QBLK    (4 * QT * 32)        // 512 queries per block
#define MT      (CSLICE / 32)        // 16 ref tiles per slice
#define SLICES  (NPTS / CSLICE)      // 16
#define QBLKS   (NPTS / QBLK)        // 16
#define FR_PER_SB 16384              // h8 frags per (side,b): 8192 pts * 2

typedef _Float16 h8   __attribute__((ext_vector_type(8)));
typedef float    f16v __attribute__((ext_vector_type(16)));

__device__ __forceinline__ void split16(float v, _Float16& hi, _Float16& lo) {
    hi = (_Float16)v;
    lo = (_Float16)(v - (float)hi);
}

__device__ __forceinline__ float tree16(const f16v& d) {
    float g0 = fminf(fminf(d[0],  d[1]),  d[2]);
    float g1 = fminf(fminf(d[3],  d[4]),  d[5]);
    float g2 = fminf(fminf(d[6],  d[7]),  d[8]);
    float g3 = fminf(fminf(d[9],  d[10]), d[11]);
    float g4 = fminf(fminf(d[12], d[13]), d[14]);
    float h0 = fminf(fminf(g0, g1), d[15]);
    float h1 = fminf(fminf(g2, g3), g4);
    return fminf(h0, h1);
}

// ---- one-shot fragment precompute (layout validated EXACT in r17) ----
// side s: 0 = x-points, 1 = y-points. Per point: a-frag pair (ref role,
// de-interleaved [group][half][row] order so a slice is one contiguous
// 16KB run = the LDS image) and b-frag pair (query role, indexed [qi][hv]).
__global__ __launch_bounds__(TPB) void chamfer_presplit(const float* __restrict__ xg,
                                                        const float* __restrict__ yg,
                                                        h8* __restrict__ aArr,
                                                        h8* __restrict__ bArr,
                                                        float* __restrict__ out) {
    const int tid = threadIdx.x;
    const int g   = blockIdx.x * TPB + tid;        // [0, BATCH*NPTS)
    if (blockIdx.x == 0 && tid == 0) out[0] = 0.0f;   // reduce runs after (stream order)
    const int b = g >> 13, i = g & (NPTS - 1);
#pragma unroll
    for (int s = 0; s < 2; ++s) {
        const float* p = (s ? yg : xg) + ((size_t)b * NPTS + i) * 3;
        float c0 = p[0], c1 = p[1], c2 = p[2];
        _Float16 h0, l0, h1, l1, h2, l2, nh, nl, H0, L0, H1, L1, H2, L2;
        split16(c0, h0, l0);                       // a-side: RAW coords
        split16(c1, h1, l1);
        split16(c2, h2, l2);
        split16(fmaf(c0, c0, fmaf(c1, c1, c2 * c2)), nh, nl);  // |p|^2 (rn == qn)
        split16(-2.0f * c0, H0, L0);               // b-side: -2q, split AFTER scaling
        split16(-2.0f * c1, H1, L1);
        split16(-2.0f * c2, H2, L2);
        const size_t base = (size_t)(s * BATCH + b) * FR_PER_SB;
        aArr[base + (i >> 5) * 64 + (i & 31)]      =
            (h8){h0, h1, h2, l0, l1, l2, h0, h1};                           // k0..7
        aArr[base + (i >> 5) * 64 + 32 + (i & 31)] =
            (h8){h2, nh, nl, (_Float16)1.0f, (_Float16)1.0f,
                 (_Float16)0.0f, (_Float16)0.0f, (_Float16)0.0f};           // k8..15
        bArr[base + i * 2]     =
            (h8){H0, H1, H2, H0, H1, H2, L0, L1};                           // k0..7
        bArr[base + i * 2 + 1] =
            (h8){L2, (_Float16)1.0f, (_Float16)1.0f, nh, nl,
                 (_Float16)0.0f, (_Float16)0.0f, (_Float16)0.0f};           // k8..15
    }
}

__global__ __launch_bounds__(TPB, 8) void chamfer_mfma(const h8* __restrict__ aArr,
                                                       const h8* __restrict__ bArr,
                                                       float* __restrict__ partial) {
    __shared__ h8 afrag[CSLICE * 2];          // 16 KB, de-interleaved (conflict-free)

    const int tid    = threadIdx.x;
    const int qblock = blockIdx.x;            // [0,16)
    const int slice  = blockIdx.y & (SLICES - 1);
    const int b      = blockIdx.y >> 4;       // SLICES == 16
    const int dir    = blockIdx.z;
    const int lane   = tid & 63, wave = tid >> 6;
    const int col    = lane & 31, hv = lane >> 5;

    const int sa = dir ? 0 : 1;               // ref side:   dir0 -> y, dir1 -> x
    const int sb = dir ? 1 : 0;               // query side

    // ---- stage ref A-frags: pure 16B vector copy of the precomputed image ----
    const h8* asrc = aArr + (size_t)(sa * BATCH + b) * FR_PER_SB + slice * (CSLICE * 2);
#pragma unroll
    for (int i2 = 0; i2 < (CSLICE * 2) / TPB; ++i2)            // 4x 16B per thread
        afrag[tid + i2 * TPB] = asrc[tid + i2 * TPB];

    // ---- query B-frags: one 16B load per tile (hv-selected half) ----
    const h8* bsrc = bArr + (size_t)(sb * BATCH + b) * FR_PER_SB;
    h8 bq[QT];
#pragma unroll
    for (int t = 0; t < QT; ++t) {
        const int qi = qblock * QBLK + (wave * QT + t) * 32 + col;
        bq[t] = bsrc[qi * 2 + hv];
    }
    __syncthreads();

    float cm[QT];
#pragma unroll
    for (int t = 0; t < QT; ++t) cm[t] = 3.0e38f;

    // ---- main loop: 1 A-frag read -> 2x (2 MFMAs + 2 trees); d-pair live only ----
    for (int mt = 0; mt < MT; ++mt) {
        const h8 ar = afrag[mt * 64 + lane];   // contiguous 16B/lane, conflict-free
        f16v d0, d1;
        asm("v_mfma_f32_32x32x16_f16 %0, %2, %3, 0\n\t"
            "v_mfma_f32_32x32x16_f16 %1, %2, %4, 0\n\t"
            "s_nop 7\n\t"
            "s_nop 7"
            : "=v"(d0), "=v"(d1)
            : "v"(ar), "v"(bq[0]), "v"(bq[1]));
        cm[0] = fminf(cm[0], tree16(d0));
        cm[1] = fminf(cm[1], tree16(d1));

        f16v d2, d3;
        asm("v_mfma_f32_32x32x16_f16 %0, %2, %3, 0\n\t"
            "v_mfma_f32_32x32x16_f16 %1, %2, %4, 0\n\t"
            "s_nop 7\n\t"
            "s_nop 7"
            : "=v"(d2), "=v"(d3)
            : "v"(ar), "v"(bq[2]), "v"(bq[3]));
        cm[2] = fminf(cm[2], tree16(d2));
        cm[3] = fminf(cm[3], tree16(d3));
    }

    // ---- epilogue: one xor32 per accumulator, coalesced stores ----
    float* pp = partial + ((size_t)(dir * BATCH + b) * SLICES + slice) * NPTS
                        + qblock * QBLK;
#pragma unroll
    for (int t = 0; t < QT; ++t) {
        cm[t] = fminf(cm[t], __shfl_xor(cm[t], 32, 64));   // hv-partner rows
        if (hv == 0)
            pp[(wave * QT + t) * 32 + col] = cm[t];        // 32 lanes, 128B coalesced
    }
}

__global__ __launch_bounds__(TPB) void chamfer_reduce(const float* __restrict__ partial,
                                                      float* __restrict__ out) {
    const int tid = threadIdx.x;
    const int g   = blockIdx.x * TPB + tid;   // [0, 2*BATCH*NPTS)
    const int db  = g >> 13;                  // (dir*BATCH + b)
    const int n   = g & (NPTS - 1);

    const float* p = partial + (size_t)db * SLICES * NPTS + n;
    float v = 3.0e38f;
#pragma unroll
    for (int s = 0; s < SLICES; ++s)
        v = fminf(v, p[(size_t)s * NPTS]);    // coalesced across threads

    float w = v;
#pragma unroll
    for (int off = 32; off > 0; off >>= 1)
        w += __shfl_down(w, off, 64);
    __shared__ float ss[TPB / 64];
    if ((tid & 63) == 0) ss[tid >> 6] = w;
    __syncthreads();
    if (tid == 0)
        atomicAdd(out, (ss[0] + ss[1] + ss[2] + ss[3]) * (1.0f / (float)(BATCH * NPTS)));
}

extern "C" void kernel_launch(void* const* d_in, const int* in_sizes, int n_in,
                              void* d_out, int out_size, void* d_ws, size_t ws_size,
                              hipStream_t stream) {
    const float* x = (const float*)d_in[0];
    const float* y = (const float*)d_in[1];
    float* out = (float*)d_out;
    char* ws = (char*)d_ws;
    float* partial = (float*)ws;                    // 4 MB
    h8*    aArr    = (h8*)(ws + (4u << 20));        // 2 MB (2 sides x 4 b x 16K h8)
    h8*    bArr    = (h8*)(ws + (6u << 20));        // 2 MB

    chamfer_presplit<<<dim3(BATCH * NPTS / TPB), TPB, 0, stream>>>(x, y, aArr, bArr, out);
    chamfer_mfma<<<dim3(QBLKS, BATCH * SLICES, 2), TPB, 0, stream>>>(aArr, bArr, partial);
    chamfer_reduce<<<dim3(2 * BATCH * NPTS / TPB), TPB, 0, stream>>>(partial, out);
}